// Round 1
// baseline (269.944 us; speedup 1.0000x reference)
//
#include <hip/hip_runtime.h>

#define N_ROWS   131072
#define D_IN     256
#define D_MID    128
#define N_SUBS   64

// ---- K1 geometry: 2048 blocks x 256 threads = 8192 waves x 16 rows ----
#define K1_BLOCKS      2048
#define K1_THREADS     256
#define K1_WAVES       (K1_BLOCKS * K1_THREADS / 64)     // 8192
#define K1_ROWS_PER_W  (N_ROWS / K1_WAVES)               // 16

// ---- K2 geometry: 256 blocks x 1024 threads = 4096 waves x 32 rows ----
#define K2_BLOCKS      256
#define K2_THREADS     1024
#define K2_WAVES       (K2_BLOCKS * K2_THREADS / 64)     // 4096
#define K2_ROWS_PER_W  (N_ROWS / K2_WAVES)               // 32

// ws layout: rowsum[N_ROWS] | partials[K1_BLOCKS][128]  (64 group sums + 64 counts)

// K1: one wave per 16 rows (strided by K1_WAVES so the whole GPU streams a
// contiguous 8 MB slab per iteration). Per row: coalesced float4 load
// (16 B/lane x 64 lanes = 1 KiB), 6-step shfl_xor reduce, lane 0 stores
// rowsum and LDS-bins (sum, count) by group. Block epilogue: plain stores of
// the 128 per-block bin partials -> no global atomics, no pre-zero needed.
__global__ __launch_bounds__(256) void k1_rowsum_bins(const float* __restrict__ x,
                                                      const int* __restrict__ sub,
                                                      float* __restrict__ rowsum,
                                                      float* __restrict__ partials) {
    __shared__ float ls[2 * N_SUBS];                 // [0..63] sums, [64..127] counts
    if (threadIdx.x < 2 * N_SUBS) ls[threadIdx.x] = 0.0f;
    __syncthreads();

    int wave = (blockIdx.x * K1_THREADS + threadIdx.x) >> 6;   // global wave id
    int lane = threadIdx.x & 63;

    #pragma unroll 4
    for (int r = 0; r < K1_ROWS_PER_W; ++r) {
        int row = wave + r * K1_WAVES;
        float4 v = ((const float4*)(x + (size_t)row * D_IN))[lane];
        float s = (v.x + v.y) + (v.z + v.w);
        #pragma unroll
        for (int m = 32; m >= 1; m >>= 1) s += __shfl_xor(s, m, 64);
        if (lane == 0) {
            rowsum[row] = s;
            int g = sub[row];
            atomicAdd(&ls[g], s);                    // LDS atomic, 64 adds/block total
            atomicAdd(&ls[N_SUBS + g], 1.0f);
        }
    }
    __syncthreads();
    if (threadIdx.x < 2 * N_SUBS)
        partials[(size_t)blockIdx.x * (2 * N_SUBS) + threadIdx.x] = ls[threadIdx.x];
}

// K2: prologue reduces partials[2048][128] -> per-group s, then streams output.
// 1024 threads = 8 chunks x 128 slots; each chunk sums 256 consecutive block
// rows (fully coalesced 256 B/wave reads; the 1 MB array is L2-resident after
// the first block touches it). Then each wave writes 32 rows of broadcast o
// as float4 (1 KiB/store).
__global__ __launch_bounds__(1024) void k2_out(const float* __restrict__ rowsum,
                                               const int* __restrict__ sub,
                                               const float* __restrict__ partials,
                                               const float* __restrict__ Gamma,
                                               const float* __restrict__ Lambda,
                                               float* __restrict__ out) {
    __shared__ float red[8][2 * N_SUBS];             // chunk partial sums
    __shared__ float tg[N_SUBS];                     // Lambda * D_MID * s[g]
    int tid = threadIdx.x;

    {   // chunked tree-reduce of the 2048 partial rows
        int slot  = tid & 127;                       // bin/count slot
        int chunk = tid >> 7;                        // 0..7
        float acc = 0.0f;
        int b0 = chunk * (K1_BLOCKS / 8);
        for (int b = b0; b < b0 + (K1_BLOCKS / 8); ++b)
            acc += partials[(size_t)b * (2 * N_SUBS) + slot];
        red[chunk][slot] = acc;
    }
    __syncthreads();
    if (tid < 2 * N_SUBS) {
        float t0 = 0.0f;
        #pragma unroll
        for (int c = 0; c < 8; ++c) t0 += red[c][tid];
        red[0][tid] = t0;
    }
    __syncthreads();
    if (tid < N_SUBS) {
        float sum = red[0][tid];
        float cnt = red[0][N_SUBS + tid];
        // empty-group fallback: mean over x[0] -> meansum == rowsum[0]
        float meansum = (cnt > 0.0f) ? (sum / cnt) : rowsum[0];
        float s = Gamma[0] * meansum;
        s = s > 0.0f ? s : 0.0f;                     // relu
        tg[tid] = Lambda[0] * (float)D_MID * s;
    }
    __syncthreads();

    float lam  = Lambda[0];
    int gw   = (blockIdx.x * K2_THREADS + tid) >> 6; // global wave id
    int lane = tid & 63;

    #pragma unroll 4
    for (int r = 0; r < K2_ROWS_PER_W; ++r) {
        int row = gw + r * K2_WAVES;
        float o = lam * rowsum[row] + tg[sub[row]];  // broadcast scalar loads
        o = o > 0.0f ? o : 0.0f;                     // relu
        ((float4*)(out + (size_t)row * D_IN))[lane] = make_float4(o, o, o, o);
    }
}

extern "C" void kernel_launch(void* const* d_in, const int* in_sizes, int n_in,
                              void* d_out, int out_size, void* d_ws, size_t ws_size,
                              hipStream_t stream) {
    const float* x      = (const float*)d_in[0];
    const int*   sub    = (const int*)d_in[1];
    const float* Gamma  = (const float*)d_in[2];
    const float* Lambda = (const float*)d_in[3];
    float* out = (float*)d_out;

    float* rowsum   = (float*)d_ws;                  // N_ROWS floats
    float* partials = rowsum + N_ROWS;               // K1_BLOCKS * 128 floats

    k1_rowsum_bins<<<K1_BLOCKS, K1_THREADS, 0, stream>>>(x, sub, rowsum, partials);
    k2_out<<<K2_BLOCKS, K2_THREADS, 0, stream>>>(rowsum, sub, partials, Gamma, Lambda, out);
}